// Round 1
// baseline (419.294 us; speedup 1.0000x reference)
//
#include <hip/hip_runtime.h>
#include <hip/hip_bf16.h>
#include <math.h>

// Problem constants (verified against in_sizes at launch where possible)
#define NNODES 50000
#define NEDGES 800000
#define IN1 512
#define IN2 256
#define NOUT 128
#define FTOT 256   // combined feature width (two GCN branches)

// ---------------- workspace layout (bytes) ----------------
// xw      : N * 256 f32   = 51,200,000
// deg     : N int         =    200,000
// dinv    : N f32         =    200,000
// rowptr  : (N+1) int     =    200,004
// cursor  : N int         =    200,000
// adj     : E int         =  3,200,000
#define OFF_XW      ((size_t)0)
#define OFF_DEG     ((size_t)51200000)
#define OFF_DINV    ((size_t)51400064)
#define OFF_ROWPTR  ((size_t)51600128)
#define OFF_CURSOR  ((size_t)51800192)
#define OFF_ADJ     ((size_t)52000256)

// ---------------- kernels ----------------

__global__ __launch_bounds__(256) void init_kernel(int* __restrict__ deg, int* __restrict__ cursor, int n) {
    int i = blockIdx.x * blockDim.x + threadIdx.x;
    if (i < n) { deg[i] = 1; cursor[i] = 0; }   // deg starts at 1: self-loop
}

__global__ __launch_bounds__(256) void hist_kernel(const int* __restrict__ ei, int* __restrict__ deg, int e) {
    int i = blockIdx.x * blockDim.x + threadIdx.x;
    if (i < e) {
        int dst = ei[e + i];          // edge_index row 1
        atomicAdd(&deg[dst], 1);
    }
}

__global__ __launch_bounds__(256) void dinv_kernel(const int* __restrict__ deg, float* __restrict__ dinv, int n) {
    int i = blockIdx.x * blockDim.x + threadIdx.x;
    if (i < n) dinv[i] = rsqrtf((float)deg[i]);
}

// single-block exclusive scan of (deg[i]-1) -> rowptr, rowptr[n] = total
__global__ __launch_bounds__(1024) void scan_kernel(const int* __restrict__ deg, int* __restrict__ rowptr, int n) {
    __shared__ int part[1024];
    const int t = threadIdx.x;
    const int CH = (n + 1023) / 1024;
    int s0 = t * CH;
    int s1 = s0 + CH; if (s1 > n) s1 = n;
    int loc = 0;
    for (int i = s0; i < s1; ++i) loc += deg[i] - 1;
    part[t] = loc;
    __syncthreads();
    for (int off = 1; off < 1024; off <<= 1) {
        int v = (t >= off) ? part[t - off] : 0;
        __syncthreads();
        part[t] += v;
        __syncthreads();
    }
    int run = (t == 0) ? 0 : part[t - 1];
    for (int i = s0; i < s1; ++i) { rowptr[i] = run; run += deg[i] - 1; }
    if (s0 <= n && s1 == n) rowptr[n] = run;
}

__global__ __launch_bounds__(256) void fill_kernel(const int* __restrict__ ei,
                                                   const int* __restrict__ rowptr,
                                                   int* __restrict__ cursor,
                                                   int* __restrict__ adj, int e) {
    int i = blockIdx.x * blockDim.x + threadIdx.x;
    if (i < e) {
        int src = ei[i];
        int dst = ei[e + i];
        int pos = rowptr[dst] + atomicAdd(&cursor[dst], 1);
        adj[pos] = src;
    }
}

// f32 tiled GEMM: XW[:, colOff:colOff+128] = X @ W   (no bias here)
// BM=128 BN=128 BK=16, 256 threads, 8x8 micro-tile
#define BM 128
#define BN 128
#define BK 16
__global__ __launch_bounds__(256) void gemm_kernel(const float* __restrict__ X1, const float* __restrict__ Wa,
                                                   const float* __restrict__ X2, const float* __restrict__ Wb,
                                                   float* __restrict__ XW, int n) {
    const float* X; const float* W; int K, colOff;
    if (blockIdx.y == 0) { X = X1; W = Wa; K = IN1; colOff = 0; }
    else                 { X = X2; W = Wb; K = IN2; colOff = 128; }

    __shared__ float As[BK][BM + 4];   // stride 132 floats: transposed store conflict-free, 16B-aligned rows
    __shared__ float Bs[BK][BN + 4];

    const int t   = threadIdx.x;
    const int ttr = t >> 4;            // 0..15 -> rows ttr*8..+7
    const int ttc = t & 15;            // 0..15 -> cols ttc*8..+7
    const int rowBase = blockIdx.x * BM;

    float acc[8][8];
    #pragma unroll
    for (int i = 0; i < 8; ++i)
        #pragma unroll
        for (int j = 0; j < 8; ++j) acc[i][j] = 0.f;

    const int a_row = t >> 1;          // 0..127
    const int a_k0  = (t & 1) * 8;     // 0 or 8
    const int b_kk  = t >> 4;          // 0..15
    const int b_c0  = (t & 15) * 8;    // 0,8,...,120

    for (int kt = 0; kt < K; kt += BK) {
        int grow = rowBase + a_row; if (grow >= n) grow = n - 1;
        const float4* ap = reinterpret_cast<const float4*>(&X[(size_t)grow * K + kt + a_k0]);
        float4 a0 = ap[0], a1 = ap[1];
        const float4* bp = reinterpret_cast<const float4*>(&W[(size_t)(kt + b_kk) * NOUT + b_c0]);
        float4 bv0 = bp[0], bv1 = bp[1];

        __syncthreads();
        As[a_k0 + 0][a_row] = a0.x; As[a_k0 + 1][a_row] = a0.y;
        As[a_k0 + 2][a_row] = a0.z; As[a_k0 + 3][a_row] = a0.w;
        As[a_k0 + 4][a_row] = a1.x; As[a_k0 + 5][a_row] = a1.y;
        As[a_k0 + 6][a_row] = a1.z; As[a_k0 + 7][a_row] = a1.w;
        *reinterpret_cast<float4*>(&Bs[b_kk][b_c0])     = bv0;
        *reinterpret_cast<float4*>(&Bs[b_kk][b_c0 + 4]) = bv1;
        __syncthreads();

        #pragma unroll
        for (int kk = 0; kk < BK; ++kk) {
            float a[8], b[8];
            *reinterpret_cast<float4*>(&a[0]) = *reinterpret_cast<const float4*>(&As[kk][ttr * 8]);
            *reinterpret_cast<float4*>(&a[4]) = *reinterpret_cast<const float4*>(&As[kk][ttr * 8 + 4]);
            *reinterpret_cast<float4*>(&b[0]) = *reinterpret_cast<const float4*>(&Bs[kk][ttc * 8]);
            *reinterpret_cast<float4*>(&b[4]) = *reinterpret_cast<const float4*>(&Bs[kk][ttc * 8 + 4]);
            #pragma unroll
            for (int i = 0; i < 8; ++i)
                #pragma unroll
                for (int j = 0; j < 8; ++j)
                    acc[i][j] = fmaf(a[i], b[j], acc[i][j]);
        }
    }

    #pragma unroll
    for (int i = 0; i < 8; ++i) {
        int grow = rowBase + ttr * 8 + i;
        if (grow < n) {
            float4 v0, v1;
            v0.x = acc[i][0]; v0.y = acc[i][1]; v0.z = acc[i][2]; v0.w = acc[i][3];
            v1.x = acc[i][4]; v1.y = acc[i][5]; v1.z = acc[i][6]; v1.w = acc[i][7];
            float* dst = &XW[(size_t)grow * FTOT + colOff + ttc * 8];
            *reinterpret_cast<float4*>(dst)     = v0;
            *reinterpret_cast<float4*>(dst + 4) = v1;
        }
    }
}

// one wave per node: CSR gather + self-loop + bias + relu + pair-add + log_softmax
__global__ __launch_bounds__(256) void gather_kernel(const float* __restrict__ xw,
                                                     const int* __restrict__ rowptr,
                                                     const int* __restrict__ adj,
                                                     const float* __restrict__ dinv,
                                                     const float* __restrict__ b1,
                                                     const float* __restrict__ b2,
                                                     float* __restrict__ out, int n) {
    int wave = (int)((blockIdx.x * (size_t)blockDim.x + threadIdx.x) >> 6);
    int lane = threadIdx.x & 63;
    if (wave >= n) return;
    const int node = wave;

    const float4* base = reinterpret_cast<const float4*>(xw);
    float4 acc = make_float4(0.f, 0.f, 0.f, 0.f);

    int s = rowptr[node], e = rowptr[node + 1];
    for (int i = s; i < e; ++i) {
        int src = adj[i];
        float w = dinv[src];
        float4 v = base[(size_t)src * 64 + lane];
        acc.x = fmaf(v.x, w, acc.x);
        acc.y = fmaf(v.y, w, acc.y);
        acc.z = fmaf(v.z, w, acc.z);
        acc.w = fmaf(v.w, w, acc.w);
    }
    float di = dinv[node];
    {   // self-loop: xw[node] * dinv[node]
        float4 v = base[(size_t)node * 64 + lane];
        acc.x = fmaf(v.x, di, acc.x);
        acc.y = fmaf(v.y, di, acc.y);
        acc.z = fmaf(v.z, di, acc.z);
        acc.w = fmaf(v.w, di, acc.w);
    }
    float4 bias = (lane < 32) ? reinterpret_cast<const float4*>(b1)[lane]
                              : reinterpret_cast<const float4*>(b2)[lane - 32];
    float4 v;
    v.x = fmaxf(fmaf(acc.x, di, bias.x), 0.f);
    v.y = fmaxf(fmaf(acc.y, di, bias.y), 0.f);
    v.z = fmaxf(fmaf(acc.z, di, bias.z), 0.f);
    v.w = fmaxf(fmaf(acc.w, di, bias.w), 0.f);

    // add the other modality half (lane ^ 32 holds features f+128)
    float4 h;
    h.x = v.x + __shfl_xor(v.x, 32);
    h.y = v.y + __shfl_xor(v.y, 32);
    h.z = v.z + __shfl_xor(v.z, 32);
    h.w = v.w + __shfl_xor(v.w, 32);

    // log_softmax over 128 values held by the 32-lane group (duplicated across halves)
    float m = fmaxf(fmaxf(h.x, h.y), fmaxf(h.z, h.w));
    #pragma unroll
    for (int off = 1; off <= 16; off <<= 1) m = fmaxf(m, __shfl_xor(m, off));
    float ssum = __expf(h.x - m) + __expf(h.y - m) + __expf(h.z - m) + __expf(h.w - m);
    #pragma unroll
    for (int off = 1; off <= 16; off <<= 1) ssum += __shfl_xor(ssum, off);
    float lse = m + __logf(ssum);

    if (lane < 32) {
        float4 y;
        y.x = h.x - lse; y.y = h.y - lse; y.z = h.z - lse; y.w = h.w - lse;
        reinterpret_cast<float4*>(out)[(size_t)node * 32 + lane] = y;
    }
}

// ---------------- launcher ----------------
extern "C" void kernel_launch(void* const* d_in, const int* in_sizes, int n_in,
                              void* d_out, int out_size, void* d_ws, size_t ws_size,
                              hipStream_t stream) {
    const float* x1 = (const float*)d_in[0];
    const float* x2 = (const float*)d_in[1];
    const int*   ei = (const int*)d_in[2];
    const float* W1 = (const float*)d_in[3];
    const float* b1 = (const float*)d_in[4];
    const float* W2 = (const float*)d_in[5];
    const float* b2 = (const float*)d_in[6];
    float* out = (float*)d_out;

    const int n = in_sizes[0] / IN1;       // 50000
    const int e = in_sizes[2] / 2;         // 800000

    char* ws = (char*)d_ws;
    float* xw     = (float*)(ws + OFF_XW);
    int*   deg    = (int*)  (ws + OFF_DEG);
    float* dinv   = (float*)(ws + OFF_DINV);
    int*   rowptr = (int*)  (ws + OFF_ROWPTR);
    int*   cursor = (int*)  (ws + OFF_CURSOR);
    int*   adj    = (int*)  (ws + OFF_ADJ);

    const int nb_n = (n + 255) / 256;
    const int nb_e = (e + 255) / 256;

    init_kernel<<<nb_n, 256, 0, stream>>>(deg, cursor, n);
    hist_kernel<<<nb_e, 256, 0, stream>>>(ei, deg, e);
    dinv_kernel<<<nb_n, 256, 0, stream>>>(deg, dinv, n);
    scan_kernel<<<1, 1024, 0, stream>>>(deg, rowptr, n);
    fill_kernel<<<nb_e, 256, 0, stream>>>(ei, rowptr, cursor, adj, e);

    dim3 ggrid((n + BM - 1) / BM, 2);
    gemm_kernel<<<ggrid, 256, 0, stream>>>(x1, W1, x2, W2, xw, n);

    const int waves_per_block = 4;
    int gb = (n + waves_per_block - 1) / waves_per_block;
    gather_kernel<<<gb, 256, 0, stream>>>(xw, rowptr, adj, dinv, b1, b2, out, n);
}

// Round 2
// 203.023 us; speedup vs baseline: 2.0653x; 2.0653x over previous
//
#include <hip/hip_runtime.h>
#include <hip/hip_bf16.h>
#include <math.h>

#define NNODES 50000
#define NEDGES 800000
#define IN1 512
#define IN2 256
#define NOUT 128
#define FTOT 256   // combined feature width (two GCN branches)

typedef __attribute__((ext_vector_type(8))) short short8;
typedef __attribute__((ext_vector_type(4))) short short4v;
typedef __attribute__((ext_vector_type(8))) short frag_ab;
typedef __attribute__((ext_vector_type(4))) float frag_cd;

// ---------------- workspace layout (bytes) ----------------
// xw   : N*256 bf16 = 25,600,000
// w1t  : 128x512 bf16 = 131,072   (W1 transposed, [col][k])
// w2t  : 128x256 bf16 =  65,536
// deg  : N int, dinv : N f32, rowptr : (N+1) int, cursor : N int
// bsum : 256 int
// adj  : E int
#define OFF_XW      ((size_t)0)
#define OFF_W1T     ((size_t)25600000)
#define OFF_W2T     ((size_t)25731072)
#define OFF_DEG     ((size_t)25796608)
#define OFF_DINV    ((size_t)25996672)
#define OFF_ROWPTR  ((size_t)26196736)
#define OFF_CURSOR  ((size_t)26396800)
#define OFF_BSUM    ((size_t)26596864)
#define OFF_ADJ     ((size_t)26600960)

__device__ __forceinline__ short f2bf(float f) {
    union { float f; unsigned u; } x; x.f = f;
    unsigned r = x.u + 0x7fffu + ((x.u >> 16) & 1u);   // RNE
    return (short)(r >> 16);
}
__device__ __forceinline__ float bf2f(unsigned short u) {
    union { unsigned u; float f; } x; x.u = ((unsigned)u) << 16;
    return x.f;
}

// ---------------- small kernels ----------------

// W transpose + f32->bf16: w1t[c][k] = W1[k][c], w2t[c][k] = W2[k][c]
__global__ __launch_bounds__(256) void wcvt_kernel(const float* __restrict__ W1, const float* __restrict__ W2,
                                                   short* __restrict__ w1t, short* __restrict__ w2t) {
    int t = blockIdx.x * 256 + threadIdx.x;
    if (t < IN1 * NOUT) {
        int c = t & 127, k = t >> 7;                 // read coalesced
        w1t[c * IN1 + k] = f2bf(W1[t]);
    } else if (t < (IN1 + IN2) * NOUT) {
        int u = t - IN1 * NOUT;
        int c = u & 127, k = u >> 7;
        w2t[c * IN2 + k] = f2bf(W2[u]);
    }
}

__global__ __launch_bounds__(256) void hist_kernel(const int* __restrict__ ei, int* __restrict__ deg, int e) {
    int i = blockIdx.x * blockDim.x + threadIdx.x;
    if (i < e) atomicAdd(&deg[ei[e + i]], 1);
}

// block partial sums of deg (real edges only) + fused dinv = rsqrt(deg+1)
__global__ __launch_bounds__(256) void scan_part_kernel(const int* __restrict__ deg, float* __restrict__ dinv,
                                                        int* __restrict__ bsum, int n) {
    __shared__ int s[256];
    int t = threadIdx.x;
    int i = blockIdx.x * 256 + t;
    int v = (i < n) ? deg[i] : 0;
    if (i < n) dinv[i] = rsqrtf((float)(v + 1));
    s[t] = v; __syncthreads();
    #pragma unroll
    for (int off = 128; off > 0; off >>= 1) {
        if (t < off) s[t] += s[t + off];
        __syncthreads();
    }
    if (t == 0) bsum[blockIdx.x] = s[0];
}

// exclusive scan of bsum[nb] in place (nb <= 256)
__global__ __launch_bounds__(256) void scan_top_kernel(int* __restrict__ bsum, int nb) {
    __shared__ int s[256];
    int t = threadIdx.x;
    int v = (t < nb) ? bsum[t] : 0;
    s[t] = v; __syncthreads();
    for (int off = 1; off < 256; off <<= 1) {
        int u = (t >= off) ? s[t - off] : 0;
        __syncthreads();
        s[t] += u;
        __syncthreads();
    }
    if (t < nb) bsum[t] = s[t] - v;
}

__global__ __launch_bounds__(256) void scan_write_kernel(const int* __restrict__ deg, const int* __restrict__ bsum,
                                                         int* __restrict__ rowptr, int n) {
    __shared__ int s[256];
    int t = threadIdx.x;
    int i = blockIdx.x * 256 + t;
    int v = (i < n) ? deg[i] : 0;
    s[t] = v; __syncthreads();
    for (int off = 1; off < 256; off <<= 1) {
        int u = (t >= off) ? s[t - off] : 0;
        __syncthreads();
        s[t] += u;
        __syncthreads();
    }
    int base = bsum[blockIdx.x];
    if (i < n) rowptr[i] = base + s[t] - v;          // exclusive
    if (i == n - 1) rowptr[n] = base + s[t];         // total = E
}

__global__ __launch_bounds__(256) void fill_kernel(const int* __restrict__ ei, const int* __restrict__ rowptr,
                                                   int* __restrict__ cursor, int* __restrict__ adj, int e) {
    int i = blockIdx.x * blockDim.x + threadIdx.x;
    if (i < e) {
        int src = ei[i];
        int dst = ei[e + i];
        int pos = rowptr[dst] + atomicAdd(&cursor[dst], 1);
        adj[pos] = src;
    }
}

// ---------------- MFMA GEMM ----------------
// XW[:, colOff:colOff+128] = bf16(X) @ bf16(W),  output stored bf16.
// 128x128 tile, BK=32, 4 waves (2x2), mfma_f32_16x16x32_bf16 with swapped
// operands so each lane owns 4 consecutive output columns (packed 8B store).
#define GBM 128
#define GBK 32
__global__ __launch_bounds__(256) void gemm_kernel(const float* __restrict__ x1, const float* __restrict__ x2,
                                                   const short* __restrict__ w1t, const short* __restrict__ w2t,
                                                   short* __restrict__ xw, int n) {
    const float* X; const short* Wt; int K, colOff;
    if (blockIdx.y == 0) { X = x1; Wt = w1t; K = IN1; colOff = 0; }
    else                 { X = x2; Wt = w2t; K = IN2; colOff = 128; }

    // [koff][row][j] layout: a wave's frag read (16 lanes per koff) is 256B contiguous
    __shared__ short As[4][128][8];   // 8 KiB
    __shared__ short Bs[4][128][8];   // 8 KiB

    const int t    = threadIdx.x;
    const int lane = t & 63;
    const int wave = t >> 6;
    const int wr   = wave >> 1;        // 0..1: row half
    const int wc   = wave & 1;         // 0..1: col half
    const int rowBase = blockIdx.x * GBM;

    frag_cd acc[4][4];
    #pragma unroll
    for (int i = 0; i < 4; ++i)
        #pragma unroll
        for (int j = 0; j < 4; ++j)
            acc[i][j] = (frag_cd){0.f, 0.f, 0.f, 0.f};

    const int arow = t >> 1;           // 0..127
    const int akp  = t & 1;            // k-half: 16 elems
    const int bcol = t & 127;          // B staging source col
    const int bkof = t >> 7;           // 0..1

    const int l15 = lane & 15, kof = lane >> 4;
    char* bs_base = (char*)&Bs[0][0][0];

    for (int kt = 0; kt < K; kt += GBK) {
        // A: global f32 -> regs
        int grow = rowBase + arow; if (grow >= n) grow = n - 1;
        const float4* ap = reinterpret_cast<const float4*>(&X[(size_t)grow * K + kt + akp * 16]);
        float4 a0 = ap[0], a1 = ap[1], a2 = ap[2], a3 = ap[3];

        __syncthreads();   // previous iteration's frag reads complete

        // B: direct global->LDS (bf16, pre-transposed). dest byte = t*16 and (256+t)*16
        {
            const void* s0 = (const void*)&Wt[(size_t)bcol * K + kt + bkof * 8];
            const void* s1 = (const void*)&Wt[(size_t)bcol * K + kt + (bkof + 2) * 8];
            __builtin_amdgcn_global_load_lds((const __attribute__((address_space(1))) void*)s0,
                (__attribute__((address_space(3))) void*)(bs_base + wave * 1024), 16, 0, 0);
            __builtin_amdgcn_global_load_lds((const __attribute__((address_space(1))) void*)s1,
                (__attribute__((address_space(3))) void*)(bs_base + 4096 + wave * 1024), 16, 0, 0);
        }

        // A: cvt + pack + 2x ds_write_b128
        short8 p0, p1;
        p0[0]=f2bf(a0.x); p0[1]=f2bf(a0.y); p0[2]=f2bf(a0.z); p0[3]=f2bf(a0.w);
        p0[4]=f2bf(a1.x); p0[5]=f2bf(a1.y); p0[6]=f2bf(a1.z); p0[7]=f2bf(a1.w);
        p1[0]=f2bf(a2.x); p1[1]=f2bf(a2.y); p1[2]=f2bf(a2.z); p1[3]=f2bf(a2.w);
        p1[4]=f2bf(a3.x); p1[5]=f2bf(a3.y); p1[6]=f2bf(a3.z); p1[7]=f2bf(a3.w);
        *reinterpret_cast<short8*>(&As[2 * akp][arow][0])     = p0;
        *reinterpret_cast<short8*>(&As[2 * akp + 1][arow][0]) = p1;

        __syncthreads();   // drains vmcnt (global_load_lds) + lgkmcnt (ds_write)

        frag_ab afr[4], bfr[4];
        #pragma unroll
        for (int mf = 0; mf < 4; ++mf)
            afr[mf] = *reinterpret_cast<const frag_ab*>(&As[kof][wr * 64 + mf * 16 + l15][0]);
        #pragma unroll
        for (int nf = 0; nf < 4; ++nf)
            bfr[nf] = *reinterpret_cast<const frag_ab*>(&Bs[kof][wc * 64 + nf * 16 + l15][0]);

        #pragma unroll
        for (int mf = 0; mf < 4; ++mf)
            #pragma unroll
            for (int nf = 0; nf < 4; ++nf)
                acc[mf][nf] = __builtin_amdgcn_mfma_f32_16x16x32_bf16(bfr[nf], afr[mf], acc[mf][nf], 0, 0, 0);
    }

    // epilogue: lane holds row = l&15, cols q*4..q*4+3 per frag -> packed 8B bf16 stores
    const int q = lane >> 4;
    #pragma unroll
    for (int mf = 0; mf < 4; ++mf) {
        int grow = rowBase + wr * 64 + mf * 16 + l15;
        if (grow < n) {
            size_t rb = (size_t)grow * FTOT + colOff + wc * 64 + q * 4;
            #pragma unroll
            for (int nf = 0; nf < 4; ++nf) {
                short4v pk;
                pk[0] = f2bf(acc[mf][nf][0]); pk[1] = f2bf(acc[mf][nf][1]);
                pk[2] = f2bf(acc[mf][nf][2]); pk[3] = f2bf(acc[mf][nf][3]);
                *reinterpret_cast<short4v*>(&xw[rb + (size_t)nf * 16]) = pk;
            }
        }
    }
}

// ---------------- gather + epilogue ----------------
// one wave per node; lane owns 4 consecutive bf16 features of the 256-wide row
__global__ __launch_bounds__(256) void gather_kernel(const unsigned short* __restrict__ xw,
                                                     const int* __restrict__ rowptr,
                                                     const int* __restrict__ adj,
                                                     const float* __restrict__ dinv,
                                                     const float* __restrict__ b1,
                                                     const float* __restrict__ b2,
                                                     float* __restrict__ out, int n) {
    int wid  = (int)((blockIdx.x * (size_t)blockDim.x + threadIdx.x) >> 6);
    int lane = threadIdx.x & 63;
    if (wid >= n) return;

    const ushort4* base = reinterpret_cast<const ushort4*>(xw);   // 64 x 8B per row
    float ax = 0.f, ay = 0.f, az = 0.f, aw = 0.f;

    int s = rowptr[wid], e = rowptr[wid + 1];
    int i = s;
    int nsrc = (i < e) ? adj[i] : 0;
    for (; i < e; ++i) {
        int src = nsrc;
        if (i + 1 < e) nsrc = adj[i + 1];           // prefetch next index
        float w = dinv[src];
        ushort4 v = base[(size_t)src * 64 + lane];
        ax = fmaf(bf2f(v.x), w, ax);
        ay = fmaf(bf2f(v.y), w, ay);
        az = fmaf(bf2f(v.z), w, az);
        aw = fmaf(bf2f(v.w), w, aw);
    }
    float di = dinv[wid];
    {   // self-loop
        ushort4 v = base[(size_t)wid * 64 + lane];
        ax = fmaf(bf2f(v.x), di, ax);
        ay = fmaf(bf2f(v.y), di, ay);
        az = fmaf(bf2f(v.z), di, az);
        aw = fmaf(bf2f(v.w), di, aw);
    }
    float4 bias = (lane < 32) ? reinterpret_cast<const float4*>(b1)[lane]
                              : reinterpret_cast<const float4*>(b2)[lane - 32];
    float4 v;
    v.x = fmaxf(fmaf(ax, di, bias.x), 0.f);
    v.y = fmaxf(fmaf(ay, di, bias.y), 0.f);
    v.z = fmaxf(fmaf(az, di, bias.z), 0.f);
    v.w = fmaxf(fmaf(aw, di, bias.w), 0.f);

    float4 h;
    h.x = v.x + __shfl_xor(v.x, 32);
    h.y = v.y + __shfl_xor(v.y, 32);
    h.z = v.z + __shfl_xor(v.z, 32);
    h.w = v.w + __shfl_xor(v.w, 32);

    float m = fmaxf(fmaxf(h.x, h.y), fmaxf(h.z, h.w));
    #pragma unroll
    for (int off = 1; off <= 16; off <<= 1) m = fmaxf(m, __shfl_xor(m, off));
    float ssum = __expf(h.x - m) + __expf(h.y - m) + __expf(h.z - m) + __expf(h.w - m);
    #pragma unroll
    for (int off = 1; off <= 16; off <<= 1) ssum += __shfl_xor(ssum, off);
    float lse = m + __logf(ssum);

    if (lane < 32) {
        float4 y;
        y.x = h.x - lse; y.y = h.y - lse; y.z = h.z - lse; y.w = h.w - lse;
        reinterpret_cast<float4*>(out)[(size_t)wid * 32 + lane] = y;
    }
}

// ---------------- launcher ----------------
extern "C" void kernel_launch(void* const* d_in, const int* in_sizes, int n_in,
                              void* d_out, int out_size, void* d_ws, size_t ws_size,
                              hipStream_t stream) {
    const float* x1 = (const float*)d_in[0];
    const float* x2 = (const float*)d_in[1];
    const int*   ei = (const int*)d_in[2];
    const float* W1 = (const float*)d_in[3];
    const float* b1 = (const float*)d_in[4];
    const float* W2 = (const float*)d_in[5];
    const float* b2 = (const float*)d_in[6];
    float* out = (float*)d_out;

    const int n = in_sizes[0] / IN1;       // 50000
    const int e = in_sizes[2] / 2;         // 800000

    char* ws = (char*)d_ws;
    short* xw     = (short*)(ws + OFF_XW);
    short* w1t    = (short*)(ws + OFF_W1T);
    short* w2t    = (short*)(ws + OFF_W2T);
    int*   deg    = (int*)  (ws + OFF_DEG);
    float* dinv   = (float*)(ws + OFF_DINV);
    int*   rowptr = (int*)  (ws + OFF_ROWPTR);
    int*   cursor = (int*)  (ws + OFF_CURSOR);
    int*   bsum   = (int*)  (ws + OFF_BSUM);
    int*   adj    = (int*)  (ws + OFF_ADJ);

    const int nb_n = (n + 255) / 256;      // 196
    const int nb_e = (e + 255) / 256;

    hipMemsetAsync(deg, 0, (size_t)n * sizeof(int), stream);
    hipMemsetAsync(cursor, 0, (size_t)n * sizeof(int), stream);

    wcvt_kernel<<<((IN1 + IN2) * NOUT + 255) / 256, 256, 0, stream>>>(W1, W2, w1t, w2t);
    hist_kernel<<<nb_e, 256, 0, stream>>>(ei, deg, e);
    scan_part_kernel<<<nb_n, 256, 0, stream>>>(deg, dinv, bsum, n);
    scan_top_kernel<<<1, 256, 0, stream>>>(bsum, nb_n);
    scan_write_kernel<<<nb_n, 256, 0, stream>>>(deg, bsum, rowptr, n);
    fill_kernel<<<nb_e, 256, 0, stream>>>(ei, rowptr, cursor, adj, e);

    dim3 ggrid((n + GBM - 1) / GBM, 2);
    gemm_kernel<<<ggrid, 256, 0, stream>>>(x1, x2, w1t, w2t, xw, n);

    const int waves_per_block = 4;
    int gb = (n + waves_per_block - 1) / waves_per_block;
    gather_kernel<<<gb, 256, 0, stream>>>((const unsigned short*)xw, rowptr, adj, dinv, b1, b2, out, n);
}